// Round 1
// baseline (291.483 us; speedup 1.0000x reference)
//
#include <hip/hip_runtime.h>

#define N_PTS 4096
#define ICP_STEPS 10
#define NN_BLOCKS 1024   // 4 queries per block (1 wave each)
#define POWER_ITERS 60

// ---------------------------------------------------------------------------
// Kernel A: brute-force 1-NN + per-block partial sums for Kabsch.
// Block = 256 threads = 4 waves; wave w handles query q = blockIdx*4 + w.
// Lanes split the 4096 candidates 64-way (j = lane + 64k), then butterfly
// argmin with JAX tie-break (equal dist -> smaller index).
// Partials per block: [S1(3), S2(3), M(9), pad] where S1=sum src, S2=sum match,
// M = sum src (x) match.
// ---------------------------------------------------------------------------
__global__ __launch_bounds__(256) void nn_partial(const float* __restrict__ pc,
                                                  const float* __restrict__ p2,
                                                  float* __restrict__ partials) {
    __shared__ __align__(16) float sp2[N_PTS * 3];  // 48 KB
    __shared__ float red[4][16];

    const int tid = threadIdx.x;

    // Stage p2 into LDS with float4 loads (12288 floats = 3072 float4).
    const float4* __restrict__ p2v = (const float4*)p2;
    float4* sv = (float4*)sp2;
    for (int i = tid; i < (N_PTS * 3) / 4; i += 256) sv[i] = p2v[i];
    __syncthreads();

    const int wave = tid >> 6;
    const int lane = tid & 63;
    const int q = blockIdx.x * 4 + wave;

    const float qx = pc[3 * q + 0];
    const float qy = pc[3 * q + 1];
    const float qz = pc[3 * q + 2];

    float best = 3.4e38f;
    int bi = 0;
    #pragma unroll 4
    for (int k = 0; k < N_PTS / 64; ++k) {
        const int j = lane + (k << 6);
        const float dx = qx - sp2[3 * j + 0];
        const float dy = qy - sp2[3 * j + 1];
        const float dz = qz - sp2[3 * j + 2];
        const float d = dx * dx + dy * dy + dz * dz;
        // ascending j with strict < keeps smallest index on ties within lane
        if (d < best) { best = d; bi = j; }
    }
    // wave-wide argmin, tie -> smaller index (matches jnp.argmin)
    for (int off = 32; off; off >>= 1) {
        const float ov = __shfl_xor(best, off, 64);
        const int oi = __shfl_xor(bi, off, 64);
        if (ov < best || (ov == best && oi < bi)) { best = ov; bi = oi; }
    }

    if (lane == 0) {
        const float mx = sp2[3 * bi + 0];
        const float my = sp2[3 * bi + 1];
        const float mz = sp2[3 * bi + 2];
        float* r = red[wave];
        r[0] = qx;  r[1] = qy;  r[2] = qz;
        r[3] = mx;  r[4] = my;  r[5] = mz;
        r[6] = qx * mx;  r[7] = qx * my;  r[8] = qx * mz;
        r[9] = qy * mx;  r[10] = qy * my; r[11] = qy * mz;
        r[12] = qz * mx; r[13] = qz * my; r[14] = qz * mz;
        r[15] = 0.0f;
    }
    __syncthreads();
    if (tid < 16) {
        partials[blockIdx.x * 16 + tid] =
            red[0][tid] + red[1][tid] + red[2][tid] + red[3][tid];
    }
}

// ---------------------------------------------------------------------------
// Direct-pair partials for the final Kabsch (a[n] <-> b[n]).
// Grid: 16 blocks x 256 threads, one point per thread.
// ---------------------------------------------------------------------------
__global__ __launch_bounds__(256) void pair_partial(const float* __restrict__ a,
                                                    const float* __restrict__ b,
                                                    float* __restrict__ partials) {
    __shared__ float red[256][16];
    const int tid = threadIdx.x;
    const int p = blockIdx.x * 256 + tid;

    const float ax = a[3 * p + 0], ay = a[3 * p + 1], az = a[3 * p + 2];
    const float bx = b[3 * p + 0], by = b[3 * p + 1], bz = b[3 * p + 2];

    float* r = red[tid];
    r[0] = ax;  r[1] = ay;  r[2] = az;
    r[3] = bx;  r[4] = by;  r[5] = bz;
    r[6] = ax * bx;  r[7] = ax * by;  r[8] = ax * bz;
    r[9] = ay * bx;  r[10] = ay * by; r[11] = ay * bz;
    r[12] = az * bx; r[13] = az * by; r[14] = az * bz;
    r[15] = 0.0f;
    __syncthreads();
    for (int s = 128; s; s >>= 1) {
        if (tid < s) {
            for (int i = 0; i < 16; ++i) red[tid][i] += red[tid + s][i];
        }
        __syncthreads();
    }
    if (tid < 16) partials[blockIdx.x * 16 + tid] = red[0][tid];
}

// ---------------------------------------------------------------------------
// Kernel B: reduce partials -> H; Horn quaternion solve (shifted power
// iteration on the 4x4 N matrix); then either transform pc in place (mode 0)
// or write [R|t] (row-major 3x4) to out (mode 1).
// Single block of 256 threads; solve done redundantly in all threads.
// ---------------------------------------------------------------------------
__global__ __launch_bounds__(256) void solve_k(const float* __restrict__ partials,
                                               int nblk,
                                               float* __restrict__ pc,
                                               float* __restrict__ out,
                                               int mode) {
    __shared__ float red[256][16];
    const int tid = threadIdx.x;

    float acc[16];
    #pragma unroll
    for (int i = 0; i < 16; ++i) acc[i] = 0.0f;
    for (int r = tid; r < nblk; r += 256) {
        const float* p = partials + r * 16;
        #pragma unroll
        for (int i = 0; i < 16; ++i) acc[i] += p[i];
    }
    #pragma unroll
    for (int i = 0; i < 16; ++i) red[tid][i] = acc[i];
    __syncthreads();
    for (int s = 128; s; s >>= 1) {
        if (tid < s) {
            for (int i = 0; i < 16; ++i) red[tid][i] += red[tid + s][i];
        }
        __syncthreads();
    }

    const float S1x = red[0][0], S1y = red[0][1], S1z = red[0][2];
    const float S2x = red[0][3], S2y = red[0][4], S2z = red[0][5];
    const float Mxx = red[0][6], Mxy = red[0][7], Mxz = red[0][8];
    const float Myx = red[0][9], Myy = red[0][10], Myz = red[0][11];
    const float Mzx = red[0][12], Mzy = red[0][13], Mzz = red[0][14];

    const float invN = 1.0f / (float)N_PTS;
    const float c1x = S1x * invN, c1y = S1y * invN, c1z = S1z * invN;
    const float c2x = S2x * invN, c2y = S2y * invN, c2z = S2z * invN;

    // H[a][b] = sum (s_a - c1_a)(d_b - c2_b) = M[a][b] - S1_a * S2_b / N
    const float Sxx = Mxx - S1x * S2x * invN;
    const float Sxy = Mxy - S1x * S2y * invN;
    const float Sxz = Mxz - S1x * S2z * invN;
    const float Syx = Myx - S1y * S2x * invN;
    const float Syy = Myy - S1y * S2y * invN;
    const float Syz = Myz - S1y * S2z * invN;
    const float Szx = Mzx - S1z * S2x * invN;
    const float Szy = Mzy - S1z * S2y * invN;
    const float Szz = Mzz - S1z * S2z * invN;

    // Horn's 4x4 symmetric N matrix
    const float N00 = Sxx + Syy + Szz;
    const float N01 = Syz - Szy;
    const float N02 = Szx - Sxz;
    const float N03 = Sxy - Syx;
    const float N11 = Sxx - Syy - Szz;
    const float N12 = Sxy + Syx;
    const float N13 = Szx + Sxz;
    const float N22 = -Sxx + Syy - Szz;
    const float N23 = Syz + Szy;
    const float N33 = -Sxx - Syy + Szz;

    const float fro = sqrtf(N00 * N00 + N11 * N11 + N22 * N22 + N33 * N33 +
                            2.0f * (N01 * N01 + N02 * N02 + N03 * N03 +
                                    N12 * N12 + N13 * N13 + N23 * N23));
    const float sg = fro + 1e-20f;

    float q0 = 1.0f, q1 = 0.0f, q2 = 0.0f, q3 = 0.0f;
    for (int it = 0; it < POWER_ITERS; ++it) {
        const float r0 = N00 * q0 + N01 * q1 + N02 * q2 + N03 * q3 + sg * q0;
        const float r1 = N01 * q0 + N11 * q1 + N12 * q2 + N13 * q3 + sg * q1;
        const float r2 = N02 * q0 + N12 * q1 + N22 * q2 + N23 * q3 + sg * q2;
        const float r3 = N03 * q0 + N13 * q1 + N23 * q2 + N33 * q3 + sg * q3;
        const float inv = rsqrtf(r0 * r0 + r1 * r1 + r2 * r2 + r3 * r3 + 1e-30f);
        q0 = r0 * inv; q1 = r1 * inv; q2 = r2 * inv; q3 = r3 * inv;
    }

    const float xx = q1 * q1, yy = q2 * q2, zz = q3 * q3;
    const float xy = q1 * q2, xz = q1 * q3, yz = q2 * q3;
    const float wx = q0 * q1, wy = q0 * q2, wz = q0 * q3;
    const float R00 = 1.0f - 2.0f * (yy + zz), R01 = 2.0f * (xy - wz), R02 = 2.0f * (xz + wy);
    const float R10 = 2.0f * (xy + wz), R11 = 1.0f - 2.0f * (xx + zz), R12 = 2.0f * (yz - wx);
    const float R20 = 2.0f * (xz - wy), R21 = 2.0f * (yz + wx), R22 = 1.0f - 2.0f * (xx + yy);

    const float tx = c2x - (R00 * c1x + R01 * c1y + R02 * c1z);
    const float ty = c2y - (R10 * c1x + R11 * c1y + R12 * c1z);
    const float tz = c2z - (R20 * c1x + R21 * c1y + R22 * c1z);

    if (mode == 0) {
        for (int p = tid; p < N_PTS; p += 256) {
            const float x = pc[3 * p + 0], y = pc[3 * p + 1], z = pc[3 * p + 2];
            pc[3 * p + 0] = R00 * x + R01 * y + R02 * z + tx;
            pc[3 * p + 1] = R10 * x + R11 * y + R12 * z + ty;
            pc[3 * p + 2] = R20 * x + R21 * y + R22 * z + tz;
        }
    } else if (tid == 0) {
        out[0] = R00; out[1] = R01; out[2]  = R02; out[3]  = tx;
        out[4] = R10; out[5] = R11; out[6]  = R12; out[7]  = ty;
        out[8] = R20; out[9] = R21; out[10] = R22; out[11] = tz;
    }
}

extern "C" void kernel_launch(void* const* d_in, const int* in_sizes, int n_in,
                              void* d_out, int out_size, void* d_ws, size_t ws_size,
                              hipStream_t stream) {
    const float* p1 = (const float*)d_in[0];
    const float* p2 = (const float*)d_in[1];
    float* out = (float*)d_out;

    float* pc = (float*)d_ws;                                   // 4096*3 floats = 48 KB
    float* partials = (float*)((char*)d_ws + N_PTS * 3 * sizeof(float));  // 1024*16 floats

    // pc <- p1
    hipMemcpyAsync(pc, p1, N_PTS * 3 * sizeof(float), hipMemcpyDeviceToDevice, stream);

    for (int s = 0; s < ICP_STEPS; ++s) {
        nn_partial<<<NN_BLOCKS, 256, 0, stream>>>(pc, p2, partials);
        solve_k<<<1, 256, 0, stream>>>(partials, NN_BLOCKS, pc, nullptr, 0);
    }

    // final Kabsch: p1 -> pc
    pair_partial<<<16, 256, 0, stream>>>(p1, pc, partials);
    solve_k<<<1, 256, 0, stream>>>(partials, 16, pc, out, 1);
}